// Round 1
// baseline (188.452 us; speedup 1.0000x reference)
//
#include <hip/hip_runtime.h>
#include <math.h>

#define NATOMS   128
#define NSEG     7875
#define M_TRIU   8126      // (n*n-n)/2 - 2
#define PADLEN   8128      // M_TRIU + 2
#define OUT_PER_B 16256    // 2 * PADLEN
#define BLOCK    256

struct F3 { float x, y, z; };
__device__ __forceinline__ F3 f3sub(F3 a, F3 b) { return {a.x - b.x, a.y - b.y, a.z - b.z}; }
__device__ __forceinline__ F3 f3cross(F3 a, F3 b) {
    return {a.y * b.z - a.z * b.y, a.z * b.x - a.x * b.z, a.x * b.y - a.y * b.x};
}
__device__ __forceinline__ float f3dot(F3 a, F3 b) { return a.x * b.x + a.y * b.y + a.z * b.z; }
__device__ __forceinline__ F3 f3norm(F3 a) {
    float n = sqrtf(f3dot(a, a));
    return {a.x / n, a.y / n, a.z / n};
}
__device__ __forceinline__ float clip1(float x) { return fminf(1.0f, fmaxf(-1.0f, x)); }

// One block per batch element. Everything (atom coords + triu accumulator)
// lives in LDS: 128*3*4 B + 8126*4 B ~= 34 KB (fits; 160 KB/CU).
__global__ __launch_bounds__(BLOCK) void writhe_fused(
    const float* __restrict__ xyz,       // (B, 128, 3)
    const int4*  __restrict__ segments,  // (7875, 4): i, i+1, j, j+1
    const int4*  __restrict__ indices,   // (7875, 4): triu slots (pidx-1)
    const int*   __restrict__ sortv,     // (16256,)
    float*       __restrict__ out)       // (B, 16256)
{
    __shared__ float sx[NATOMS], sy[NATOMS], sz[NATOMS];
    __shared__ float triu[M_TRIU];

    const int b = blockIdx.x;
    const int t = threadIdx.x;

    // Stage this batch's coordinates (SoA in LDS).
    if (t < NATOMS) {
        const float* p = xyz + ((size_t)b * NATOMS + t) * 3;
        sx[t] = p[0];
        sy[t] = p[1];
        sz[t] = p[2];
    }
    // Zero the triu accumulator.
    for (int m = t; m < M_TRIU; m += BLOCK) triu[m] = 0.0f;
    __syncthreads();

    // Per-segment writhe + LDS scatter-add.
    for (int s = t; s < NSEG; s += BLOCK) {
        int4 seg = segments[s];
        int i = seg.x, j = seg.z;
        F3 p0 = {sx[i],     sy[i],     sz[i]};
        F3 p1 = {sx[i + 1], sy[i + 1], sz[i + 1]};
        F3 p2 = {sx[j],     sy[j],     sz[j]};
        F3 p3 = {sx[j + 1], sy[j + 1], sz[j + 1]};

        // d0=unit(p2-p0), d1=unit(p3-p0), d2=unit(p2-p1), d3=unit(p3-p1)
        F3 d0 = f3norm(f3sub(p2, p0));
        F3 d1 = f3norm(f3sub(p3, p0));
        F3 d2 = f3norm(f3sub(p2, p1));
        F3 d3 = f3norm(f3sub(p3, p1));

        // sign(dot(cross(p3-p2, p1-p0), d0))
        F3 axial = f3cross(f3sub(p3, p2), f3sub(p1, p0));
        float sd = f3dot(axial, d0);
        float sgn = (sd > 0.0f) ? 1.0f : ((sd < 0.0f) ? -1.0f : 0.0f);

        // n0=unit(d0×d1), n1=unit(d1×d3), n2=unit(d3×d2), n3=unit(d2×d0)
        F3 n0 = f3norm(f3cross(d0, d1));
        F3 n1 = f3norm(f3cross(d1, d3));
        F3 n2 = f3norm(f3cross(d3, d2));
        F3 n3 = f3norm(f3cross(d2, d0));

        float c0 = clip1(f3dot(n0, n1));
        float c1 = clip1(f3dot(n1, n2));
        float c2 = clip1(f3dot(n2, n3));
        float c3 = clip1(f3dot(n3, n0));

        float omega = asinf(c0) + asinf(c1) + asinf(c2) + asinf(c3);
        float wr = omega * sgn * 0.15915494309189535f;  // / (2*pi)

        int4 idx = indices[s];
        atomicAdd(&triu[idx.x], wr);
        atomicAdd(&triu[idx.y], wr);
        atomicAdd(&triu[idx.z], wr);
        atomicAdd(&triu[idx.w], wr);
    }
    __syncthreads();

    // Gather: out[k] = padded2[sort[k]] where padded2 = [0, triu, 0] twice.
    float* ob = out + (size_t)b * OUT_PER_B;
    for (int k = t; k < OUT_PER_B; k += BLOCK) {
        int v = sortv[k];
        int p = (v >= PADLEN) ? (v - PADLEN) : v;
        float val = (p == 0 || p == PADLEN - 1) ? 0.0f : triu[p - 1];
        ob[k] = val;
    }
}

extern "C" void kernel_launch(void* const* d_in, const int* in_sizes, int n_in,
                              void* d_out, int out_size, void* d_ws, size_t ws_size,
                              hipStream_t stream) {
    const float* xyz      = (const float*)d_in[0];
    const int4*  segments = (const int4*)d_in[1];
    const int4*  indices  = (const int4*)d_in[2];
    const int*   sortv    = (const int*)d_in[3];
    float*       out      = (float*)d_out;

    int B = in_sizes[0] / (NATOMS * 3);   // 512 for the reference shapes
    writhe_fused<<<B, BLOCK, 0, stream>>>(xyz, segments, indices, sortv, out);
}

// Round 2
// 159.139 us; speedup vs baseline: 1.1842x; 1.1842x over previous
//
#include <hip/hip_runtime.h>
#include <math.h>

#define NATOMS    128
#define NSEG      7875
#define M_TRIU    8126      // (n*n-n)/2 - 2
#define PADLEN    8128      // M_TRIU + 2
#define OUT_PER_B 16256     // 2 * PADLEN
#define BLOCK     1024

struct F3 { float x, y, z; };
__device__ __forceinline__ F3 f3sub(F3 a, F3 b) { return {a.x - b.x, a.y - b.y, a.z - b.z}; }
__device__ __forceinline__ F3 f3cross(F3 a, F3 b) {
    return {a.y * b.z - a.z * b.y, a.z * b.x - a.x * b.z, a.x * b.y - a.y * b.x};
}
__device__ __forceinline__ float f3dot(F3 a, F3 b) { return a.x * b.x + a.y * b.y + a.z * b.z; }
// rsqrt-based normalize: v_rsq_f32 + 3 muls instead of sqrt + 3 divides.
__device__ __forceinline__ F3 f3norm(F3 a) {
    float rn = rsqrtf(f3dot(a, a));
    return {a.x * rn, a.y * rn, a.z * rn};
}
__device__ __forceinline__ float clip1(float x) { return fminf(1.0f, fmaxf(-1.0f, x)); }

// Branchless asin for x in [-1,1]: Abramowitz & Stegun 4.4.46 (|err| ~ 2e-8).
// asin(|x|) = pi/2 - sqrt(1-|x|) * poly(|x|); odd-extend via copysign.
__device__ __forceinline__ float fast_asin(float x) {
    float a = fabsf(x);
    float p = -0.0012624911f;
    p = fmaf(p, a,  0.0066700901f);
    p = fmaf(p, a, -0.0170881256f);
    p = fmaf(p, a,  0.0308918810f);
    p = fmaf(p, a, -0.0501743046f);
    p = fmaf(p, a,  0.0889789874f);
    p = fmaf(p, a, -0.2145988016f);
    p = fmaf(p, a,  1.5707963050f);
    float r = 1.57079632679f - sqrtf(1.0f - a) * p;
    return copysignf(r, x);
}

// One block per batch element; 1024 threads => 16 waves/block, 2 blocks/CU
// => 32 waves/CU (occupancy max). LDS: 128*3*4 + 8126*4 ~= 34 KB (2 fit).
__global__ __launch_bounds__(BLOCK, 8) void writhe_fused(
    const float* __restrict__ xyz,       // (B, 128, 3)
    const int4*  __restrict__ segments,  // (7875, 4): i, i+1, j, j+1
    const int4*  __restrict__ indices,   // (7875, 4): triu slots (pidx-1)
    const int*   __restrict__ sortv,     // (16256,)
    float*       __restrict__ out)       // (B, 16256)
{
    __shared__ float sx[NATOMS], sy[NATOMS], sz[NATOMS];
    __shared__ float triu[M_TRIU];

    const int b = blockIdx.x;
    const int t = threadIdx.x;

    if (t < NATOMS) {
        const float* p = xyz + ((size_t)b * NATOMS + t) * 3;
        sx[t] = p[0];
        sy[t] = p[1];
        sz[t] = p[2];
    }
    for (int m = t; m < M_TRIU; m += BLOCK) triu[m] = 0.0f;
    __syncthreads();

    for (int s = t; s < NSEG; s += BLOCK) {
        int4 seg = segments[s];
        int i = seg.x, j = seg.z;
        F3 p0 = {sx[i],     sy[i],     sz[i]};
        F3 p1 = {sx[i + 1], sy[i + 1], sz[i + 1]};
        F3 p2 = {sx[j],     sy[j],     sz[j]};
        F3 p3 = {sx[j + 1], sy[j + 1], sz[j + 1]};

        F3 d0 = f3norm(f3sub(p2, p0));
        F3 d1 = f3norm(f3sub(p3, p0));
        F3 d2 = f3norm(f3sub(p2, p1));
        F3 d3 = f3norm(f3sub(p3, p1));

        F3 axial = f3cross(f3sub(p3, p2), f3sub(p1, p0));
        float sd = f3dot(axial, d0);
        float sgn = (sd > 0.0f) ? 1.0f : ((sd < 0.0f) ? -1.0f : 0.0f);

        F3 n0 = f3norm(f3cross(d0, d1));
        F3 n1 = f3norm(f3cross(d1, d3));
        F3 n2 = f3norm(f3cross(d3, d2));
        F3 n3 = f3norm(f3cross(d2, d0));

        float c0 = clip1(f3dot(n0, n1));
        float c1 = clip1(f3dot(n1, n2));
        float c2 = clip1(f3dot(n2, n3));
        float c3 = clip1(f3dot(n3, n0));

        float omega = fast_asin(c0) + fast_asin(c1) + fast_asin(c2) + fast_asin(c3);
        float wr = omega * sgn * 0.15915494309189535f;  // / (2*pi)

        int4 idx = indices[s];
        atomicAdd(&triu[idx.x], wr);
        atomicAdd(&triu[idx.y], wr);
        atomicAdd(&triu[idx.z], wr);
        atomicAdd(&triu[idx.w], wr);
    }
    __syncthreads();

    float* ob = out + (size_t)b * OUT_PER_B;
    for (int k = t; k < OUT_PER_B; k += BLOCK) {
        int v = sortv[k];
        int p = (v >= PADLEN) ? (v - PADLEN) : v;
        float val = (p == 0 || p == PADLEN - 1) ? 0.0f : triu[p - 1];
        ob[k] = val;
    }
}

extern "C" void kernel_launch(void* const* d_in, const int* in_sizes, int n_in,
                              void* d_out, int out_size, void* d_ws, size_t ws_size,
                              hipStream_t stream) {
    const float* xyz      = (const float*)d_in[0];
    const int4*  segments = (const int4*)d_in[1];
    const int4*  indices  = (const int4*)d_in[2];
    const int*   sortv    = (const int*)d_in[3];
    float*       out      = (float*)d_out;

    int B = in_sizes[0] / (NATOMS * 3);   // 512 for the reference shapes
    writhe_fused<<<B, BLOCK, 0, stream>>>(xyz, segments, indices, sortv, out);
}